// Round 1
// baseline (258.871 us; speedup 1.0000x reference)
//
#include <hip/hip_runtime.h>
#include <hip/hip_bf16.h>

#define NQ     4000
#define DMODEL 256
#define NHEAD  8
#define NLVL   4
#define NPT    4
#define DHEAD  32
#define LENIN  37440

// ---------------------------------------------------------------- value GEMM
// C[M,N] = A[M,K] @ B[K,N] + bias[N], fp32, 64x64 tile, BK=16, 256 threads.
#define BM 64
#define BN 64
#define BK 16

__global__ __launch_bounds__(256) void gemm_value(
    const float* __restrict__ A, const float* __restrict__ B,
    const float* __restrict__ bias, float* __restrict__ C,
    int M, int N, int K)
{
    __shared__ float As[BK][BM];
    __shared__ float Bs[BK][BN];
    const int tid  = threadIdx.x;
    const int brow = blockIdx.y * BM;
    const int bcol = blockIdx.x * BN;
    const int ty = tid >> 4, tx = tid & 15;

    float acc[4][4] = {};

    for (int k0 = 0; k0 < K; k0 += BK) {
        {   // A tile: 64 rows x 16 k (float4 per thread)
            int row = tid >> 2, kq = (tid & 3) * 4;
            float4 av = *(const float4*)&A[(size_t)(brow + row) * K + k0 + kq];
            As[kq + 0][row] = av.x;
            As[kq + 1][row] = av.y;
            As[kq + 2][row] = av.z;
            As[kq + 3][row] = av.w;
        }
        {   // B tile: 16 k x 64 cols (float4 per thread)
            int kk = tid >> 4, col = (tid & 15) * 4;
            *(float4*)&Bs[kk][col] = *(const float4*)&B[(size_t)(k0 + kk) * N + bcol + col];
        }
        __syncthreads();
        #pragma unroll
        for (int kk = 0; kk < BK; ++kk) {
            float a[4], b[4];
            *(float4*)a = *(const float4*)&As[kk][ty * 4];
            *(float4*)b = *(const float4*)&Bs[kk][tx * 4];
            #pragma unroll
            for (int i = 0; i < 4; ++i)
                #pragma unroll
                for (int j = 0; j < 4; ++j)
                    acc[i][j] += a[i] * b[j];
        }
        __syncthreads();
    }

    float4 bv = *(const float4*)&bias[bcol + tx * 4];
    #pragma unroll
    for (int i = 0; i < 4; ++i) {
        int r = brow + ty * 4 + i;
        float4 v;
        v.x = acc[i][0] + bv.x;
        v.y = acc[i][1] + bv.y;
        v.z = acc[i][2] + bv.z;
        v.w = acc[i][3] + bv.w;
        *(float4*)&C[(size_t)r * N + bcol + tx * 4] = v;
    }
}

// ------------------------------------------- offsets + attention + locations
// One block per query, 512 threads: t<384 -> offset column t, t>=384 -> attn
// column t-384 (= h*16 + (lvl*4+p)). Softmax over 16 within 16-lane groups.
__global__ __launch_bounds__(512) void off_attn_kernel(
    const float* __restrict__ query, const float* __restrict__ refpts,
    const float* __restrict__ w_off, const float* __restrict__ b_off,
    const float* __restrict__ w_attn, const float* __restrict__ b_attn,
    float* __restrict__ loc_out, float* __restrict__ attw_out)
{
    __shared__ float qrow[DMODEL];
    const int q = blockIdx.x;
    const int tid = threadIdx.x;

    if (tid < 64)
        *(float4*)&qrow[tid * 4] = *(const float4*)&query[(size_t)q * DMODEL + tid * 4];
    __syncthreads();

    float sum;
    if (tid < 384) {
        sum = b_off[tid];
        for (int k = 0; k < DMODEL; ++k)
            sum += qrow[k] * w_off[(size_t)k * 384 + tid];
    } else {
        int c = tid - 384;
        sum = b_attn[c];
        for (int k = 0; k < DMODEL; ++k)
            sum += qrow[k] * w_attn[(size_t)k * 128 + c];
    }

    if (tid >= 384) {
        // softmax over the 16 contiguous lanes of this head
        int c = tid - 384;                 // h*16 + j, j = lvl*4+p
        float m = sum;
        #pragma unroll
        for (int o = 8; o >= 1; o >>= 1) m = fmaxf(m, __shfl_xor(m, o, 16));
        float e = expf(sum - m);
        float s = e;
        #pragma unroll
        for (int o = 8; o >= 1; o >>= 1) s += __shfl_xor(s, o, 16);
        attw_out[(size_t)q * 128 + c] = e / s;
    } else {
        // tid = ((h*NLVL+lvl)*NPT+p)*3 + c ; cubic levels so normalizer=dim
        int t2  = tid / 3;
        int lvl = (t2 / NPT) & 3;
        int c   = tid - t2 * 3;
        float norm = (float)(32 >> lvl);
        float ref  = refpts[((size_t)q * NLVL + lvl) * 3 + c];
        loc_out[(size_t)q * 384 + tid] = ref + sum / norm;
    }
}

// -------------------------------------------------------- trilinear sampling
// One block per query, 256 threads: h = tid>>5, d = tid&31.
__global__ __launch_bounds__(256) void sample_kernel(
    const float* __restrict__ value, const float* __restrict__ loc,
    const float* __restrict__ attw, float* __restrict__ out_attn)
{
    const int q = blockIdx.x;
    const int tid = threadIdx.x;
    const int h = tid >> 5, d = tid & 31;

    const int DIMS[4]  = {32, 16, 8, 4};
    const int START[4] = {0, 32768, 36864, 37376};

    const float* locq = loc  + (size_t)q * 384 + h * 48;
    const float* awq  = attw + (size_t)q * 128 + h * 16;

    float acc = 0.f;
    #pragma unroll
    for (int lvl = 0; lvl < 4; ++lvl) {
        const int   S    = DIMS[lvl];
        const float Sf   = (float)S;
        const int   base = START[lvl];
        #pragma unroll
        for (int p = 0; p < 4; ++p) {
            float lx = locq[(lvl * 4 + p) * 3 + 0];
            float ly = locq[(lvl * 4 + p) * 3 + 1];
            float lz = locq[(lvl * 4 + p) * 3 + 2];
            float aw = awq[lvl * 4 + p];
            float x = lx * Sf - 0.5f, y = ly * Sf - 0.5f, z = lz * Sf - 0.5f;
            float x0f = floorf(x), y0f = floorf(y), z0f = floorf(z);
            float fx = x - x0f, fy = y - y0f, fz = z - z0f;
            int x0 = (int)x0f, y0 = (int)y0f, z0 = (int)z0f;
            #pragma unroll
            for (int dz = 0; dz < 2; ++dz) {
                float wz = dz ? fz : 1.f - fz; int zi = z0 + dz;
                #pragma unroll
                for (int dy = 0; dy < 2; ++dy) {
                    float wy = dy ? fy : 1.f - fy; int yi = y0 + dy;
                    #pragma unroll
                    for (int dx = 0; dx < 2; ++dx) {
                        float wx = dx ? fx : 1.f - fx; int xi = x0 + dx;
                        if ((unsigned)xi < (unsigned)S &&
                            (unsigned)yi < (unsigned)S &&
                            (unsigned)zi < (unsigned)S) {
                            float cw  = wx * wy * wz * aw;
                            int   idx = (zi * S + yi) * S + xi;
                            acc += cw * value[(size_t)(base + idx) * DMODEL + h * DHEAD + d];
                        }
                    }
                }
            }
        }
    }
    out_attn[(size_t)q * DMODEL + h * DHEAD + d] = acc;
}

// ------------------------------------------------------------ output project
__global__ __launch_bounds__(256) void out_gemm(
    const float* __restrict__ X, const float* __restrict__ W,
    const float* __restrict__ bias, float* __restrict__ out)
{
    __shared__ float row[DMODEL];
    const int q = blockIdx.x, tid = threadIdx.x;
    if (tid < 64)
        *(float4*)&row[tid * 4] = *(const float4*)&X[(size_t)q * DMODEL + tid * 4];
    __syncthreads();
    float s = bias[tid];
    for (int k = 0; k < DMODEL; ++k)
        s += row[k] * W[(size_t)k * DMODEL + tid];
    out[(size_t)q * DMODEL + tid] = s;
}

extern "C" void kernel_launch(void* const* d_in, const int* in_sizes, int n_in,
                              void* d_out, int out_size, void* d_ws, size_t ws_size,
                              hipStream_t stream) {
    const float* query         = (const float*)d_in[0];
    const float* refpts        = (const float*)d_in[1];
    const float* input_flatten = (const float*)d_in[2];
    const float* w_value       = (const float*)d_in[3];
    const float* b_value       = (const float*)d_in[4];
    const float* w_off         = (const float*)d_in[5];
    const float* b_off         = (const float*)d_in[6];
    const float* w_attn        = (const float*)d_in[7];
    const float* b_attn        = (const float*)d_in[8];
    const float* w_out         = (const float*)d_in[9];
    const float* b_out         = (const float*)d_in[10];

    float* ws    = (float*)d_ws;
    float* value = ws;                               // LENIN*DMODEL = 9,584,640
    float* loc   = value + (size_t)LENIN * DMODEL;   // NQ*384      = 1,536,000
    float* attw  = loc   + (size_t)NQ * 384;         // NQ*128      =   512,000
    float* oat   = attw  + (size_t)NQ * 128;         // NQ*DMODEL   = 1,024,000
    // total ~50.6 MB of workspace

    dim3 g1(DMODEL / BN, LENIN / BM);
    gemm_value<<<g1, 256, 0, stream>>>(input_flatten, w_value, b_value, value,
                                       LENIN, DMODEL, DMODEL);
    off_attn_kernel<<<NQ, 512, 0, stream>>>(query, refpts, w_off, b_off,
                                            w_attn, b_attn, loc, attw);
    sample_kernel<<<NQ, 256, 0, stream>>>(value, loc, attw, oat);
    out_gemm<<<NQ, 256, 0, stream>>>(oat, w_out, b_out, (float*)d_out);
}

// Round 2
// 212.673 us; speedup vs baseline: 1.2172x; 1.2172x over previous
//
#include <hip/hip_runtime.h>
#include <hip/hip_bf16.h>

#define NQ     4000
#define DMODEL 256
#define NHEAD  8
#define NLVL   4
#define NPT    4
#define DHEAD  32
#define LENIN  37440
#define NOFF   384
#define NATT   128
#define NPROJ  512   // NOFF + NATT

// ---------------------------------------------------------------- value GEMM
// C[M,N] = A[M,K] @ B[K,N] + bias[N], fp32, 64x64 tile, BK=16, 256 threads.
#define BM 64
#define BN 64
#define BK 16

__global__ __launch_bounds__(256) void gemm_value(
    const float* __restrict__ A, const float* __restrict__ B,
    const float* __restrict__ bias, float* __restrict__ C,
    int M, int N, int K)
{
    __shared__ float As[BK][BM];
    __shared__ float Bs[BK][BN];
    const int tid  = threadIdx.x;
    const int brow = blockIdx.y * BM;
    const int bcol = blockIdx.x * BN;
    const int ty = tid >> 4, tx = tid & 15;

    float acc[4][4] = {};

    for (int k0 = 0; k0 < K; k0 += BK) {
        {   // A tile: 64 rows x 16 k (float4 per thread)
            int row = tid >> 2, kq = (tid & 3) * 4;
            float4 av = *(const float4*)&A[(size_t)(brow + row) * K + k0 + kq];
            As[kq + 0][row] = av.x;
            As[kq + 1][row] = av.y;
            As[kq + 2][row] = av.z;
            As[kq + 3][row] = av.w;
        }
        {   // B tile: 16 k x 64 cols (float4 per thread)
            int kk = tid >> 4, col = (tid & 15) * 4;
            *(float4*)&Bs[kk][col] = *(const float4*)&B[(size_t)(k0 + kk) * N + bcol + col];
        }
        __syncthreads();
        #pragma unroll
        for (int kk = 0; kk < BK; ++kk) {
            float a[4], b[4];
            *(float4*)a = *(const float4*)&As[kk][ty * 4];
            *(float4*)b = *(const float4*)&Bs[kk][tx * 4];
            #pragma unroll
            for (int i = 0; i < 4; ++i)
                #pragma unroll
                for (int j = 0; j < 4; ++j)
                    acc[i][j] += a[i] * b[j];
        }
        __syncthreads();
    }

    float4 bv = *(const float4*)&bias[bcol + tx * 4];
    #pragma unroll
    for (int i = 0; i < 4; ++i) {
        int r = brow + ty * 4 + i;
        float4 v;
        v.x = acc[i][0] + bv.x;
        v.y = acc[i][1] + bv.y;
        v.z = acc[i][2] + bv.z;
        v.w = acc[i][3] + bv.w;
        *(float4*)&C[(size_t)r * N + bcol + tx * 4] = v;
    }
}

// ------------------------------------------------- off+attn projection GEMM
// proj[NQ, 512] = query[NQ,256] @ [w_off | w_attn] + [b_off | b_attn]
// 64x64 tile; each col-tile lies entirely inside one weight matrix (384=6*64).
// M=4000 not divisible by 64: clamp loads, guard stores.
__global__ __launch_bounds__(256) void gemm_offattn(
    const float* __restrict__ A,
    const float* __restrict__ Woff, const float* __restrict__ Boff,
    const float* __restrict__ Watt, const float* __restrict__ Batt,
    float* __restrict__ C)
{
    __shared__ float As[BK][BM];
    __shared__ float Bs[BK][BN];
    const int tid  = threadIdx.x;
    const int brow = blockIdx.y * BM;
    const int bcol = blockIdx.x * BN;
    const int ty = tid >> 4, tx = tid & 15;

    const bool is_off = (bcol < NOFF);
    const float* B    = is_off ? Woff : Watt;
    const float* bias = is_off ? Boff : Batt;
    const int    ldb  = is_off ? NOFF : NATT;
    const int    cb   = is_off ? bcol : bcol - NOFF;

    float acc[4][4] = {};

    for (int k0 = 0; k0 < DMODEL; k0 += BK) {
        {
            int row = tid >> 2, kq = (tid & 3) * 4;
            int rg  = brow + row; if (rg >= NQ) rg = NQ - 1;
            float4 av = *(const float4*)&A[(size_t)rg * DMODEL + k0 + kq];
            As[kq + 0][row] = av.x;
            As[kq + 1][row] = av.y;
            As[kq + 2][row] = av.z;
            As[kq + 3][row] = av.w;
        }
        {
            int kk = tid >> 4, col = (tid & 15) * 4;
            *(float4*)&Bs[kk][col] = *(const float4*)&B[(size_t)(k0 + kk) * ldb + cb + col];
        }
        __syncthreads();
        #pragma unroll
        for (int kk = 0; kk < BK; ++kk) {
            float a[4], b[4];
            *(float4*)a = *(const float4*)&As[kk][ty * 4];
            *(float4*)b = *(const float4*)&Bs[kk][tx * 4];
            #pragma unroll
            for (int i = 0; i < 4; ++i)
                #pragma unroll
                for (int j = 0; j < 4; ++j)
                    acc[i][j] += a[i] * b[j];
        }
        __syncthreads();
    }

    float4 bv = *(const float4*)&bias[cb + tx * 4];
    #pragma unroll
    for (int i = 0; i < 4; ++i) {
        int r = brow + ty * 4 + i;
        if (r < NQ) {
            float4 v;
            v.x = acc[i][0] + bv.x;
            v.y = acc[i][1] + bv.y;
            v.z = acc[i][2] + bv.z;
            v.w = acc[i][3] + bv.w;
            *(float4*)&C[(size_t)r * NPROJ + bcol + tx * 4] = v;
        }
    }
}

// -------------------------------------- epilogue: locations + softmax weights
// One block per query, 512 threads. t<384: sampling location; t>=384: softmax
// over the 16 (lvl,pt) slots of head (t-384)/16 via 16-lane shfl groups.
__global__ __launch_bounds__(512) void loc_softmax_kernel(
    const float* __restrict__ proj, const float* __restrict__ refpts,
    float* __restrict__ loc_out, float* __restrict__ attw_out)
{
    const int q = blockIdx.x;
    const int tid = threadIdx.x;
    float sum = proj[(size_t)q * NPROJ + tid];

    if (tid >= NOFF) {
        int c = tid - NOFF;                // h*16 + (lvl*4+p)
        float m = sum;
        #pragma unroll
        for (int o = 8; o >= 1; o >>= 1) m = fmaxf(m, __shfl_xor(m, o, 16));
        float e = expf(sum - m);
        float s = e;
        #pragma unroll
        for (int o = 8; o >= 1; o >>= 1) s += __shfl_xor(s, o, 16);
        attw_out[(size_t)q * NATT + c] = e / s;
    } else {
        // tid = ((h*NLVL+lvl)*NPT+p)*3 + c ; cubic levels so normalizer = dim
        int t2  = tid / 3;
        int lvl = (t2 / NPT) & 3;
        int c   = tid - t2 * 3;
        float norm = (float)(32 >> lvl);
        float ref  = refpts[((size_t)q * NLVL + lvl) * 3 + c];
        loc_out[(size_t)q * NOFF + tid] = ref + sum / norm;
    }
}

// -------------------------------------------------------- trilinear sampling
// One block per query, 256 threads: h = tid>>5, d = tid&31.
__global__ __launch_bounds__(256) void sample_kernel(
    const float* __restrict__ value, const float* __restrict__ loc,
    const float* __restrict__ attw, float* __restrict__ out_attn)
{
    const int q = blockIdx.x;
    const int tid = threadIdx.x;
    const int h = tid >> 5, d = tid & 31;

    const int DIMS[4]  = {32, 16, 8, 4};
    const int START[4] = {0, 32768, 36864, 37376};

    const float* locq = loc  + (size_t)q * NOFF + h * 48;
    const float* awq  = attw + (size_t)q * NATT + h * 16;

    float acc = 0.f;
    #pragma unroll
    for (int lvl = 0; lvl < 4; ++lvl) {
        const int   S    = DIMS[lvl];
        const float Sf   = (float)S;
        const int   base = START[lvl];
        #pragma unroll
        for (int p = 0; p < 4; ++p) {
            float lx = locq[(lvl * 4 + p) * 3 + 0];
            float ly = locq[(lvl * 4 + p) * 3 + 1];
            float lz = locq[(lvl * 4 + p) * 3 + 2];
            float aw = awq[lvl * 4 + p];
            float x = lx * Sf - 0.5f, y = ly * Sf - 0.5f, z = lz * Sf - 0.5f;
            float x0f = floorf(x), y0f = floorf(y), z0f = floorf(z);
            float fx = x - x0f, fy = y - y0f, fz = z - z0f;
            int x0 = (int)x0f, y0 = (int)y0f, z0 = (int)z0f;
            #pragma unroll
            for (int dz = 0; dz < 2; ++dz) {
                float wz = dz ? fz : 1.f - fz; int zi = z0 + dz;
                #pragma unroll
                for (int dy = 0; dy < 2; ++dy) {
                    float wy = dy ? fy : 1.f - fy; int yi = y0 + dy;
                    #pragma unroll
                    for (int dx = 0; dx < 2; ++dx) {
                        float wx = dx ? fx : 1.f - fx; int xi = x0 + dx;
                        if ((unsigned)xi < (unsigned)S &&
                            (unsigned)yi < (unsigned)S &&
                            (unsigned)zi < (unsigned)S) {
                            float cw  = wx * wy * wz * aw;
                            int   idx = (zi * S + yi) * S + xi;
                            acc += cw * value[(size_t)(base + idx) * DMODEL + h * DHEAD + d];
                        }
                    }
                }
            }
        }
    }
    out_attn[(size_t)q * DMODEL + h * DHEAD + d] = acc;
}

// ------------------------------------------------------------ output project
__global__ __launch_bounds__(256) void out_gemm(
    const float* __restrict__ X, const float* __restrict__ W,
    const float* __restrict__ bias, float* __restrict__ out)
{
    __shared__ float row[DMODEL];
    const int q = blockIdx.x, tid = threadIdx.x;
    if (tid < 64)
        *(float4*)&row[tid * 4] = *(const float4*)&X[(size_t)q * DMODEL + tid * 4];
    __syncthreads();
    float s = bias[tid];
    for (int k = 0; k < DMODEL; ++k)
        s += row[k] * W[(size_t)k * DMODEL + tid];
    out[(size_t)q * DMODEL + tid] = s;
}

extern "C" void kernel_launch(void* const* d_in, const int* in_sizes, int n_in,
                              void* d_out, int out_size, void* d_ws, size_t ws_size,
                              hipStream_t stream) {
    const float* query         = (const float*)d_in[0];
    const float* refpts        = (const float*)d_in[1];
    const float* input_flatten = (const float*)d_in[2];
    const float* w_value       = (const float*)d_in[3];
    const float* b_value       = (const float*)d_in[4];
    const float* w_off         = (const float*)d_in[5];
    const float* b_off         = (const float*)d_in[6];
    const float* w_attn        = (const float*)d_in[7];
    const float* b_attn        = (const float*)d_in[8];
    const float* w_out         = (const float*)d_in[9];
    const float* b_out         = (const float*)d_in[10];

    float* ws    = (float*)d_ws;
    float* value = ws;                               // LENIN*DMODEL = 9,584,640
    float* loc   = value + (size_t)LENIN * DMODEL;   // NQ*384      = 1,536,000
    float* attw  = loc   + (size_t)NQ * NOFF;        // NQ*128      =   512,000
    float* proj  = attw  + (size_t)NQ * NATT;        // NQ*512     = 2,048,000
    float* oat   = proj;                             // alias: oat (1,024,000) reuses proj
    // total ~54.7 MB of workspace

    dim3 g1(DMODEL / BN, LENIN / BM);
    gemm_value<<<g1, 256, 0, stream>>>(input_flatten, w_value, b_value, value,
                                       LENIN, DMODEL, DMODEL);
    dim3 g2(NPROJ / BN, (NQ + BM - 1) / BM);
    gemm_offattn<<<g2, 256, 0, stream>>>(query, w_off, b_off, w_attn, b_attn, proj);
    loc_softmax_kernel<<<NQ, 512, 0, stream>>>(proj, refpts, loc, attw);
    sample_kernel<<<NQ, 256, 0, stream>>>(value, loc, attw, oat);
    out_gemm<<<NQ, 256, 0, stream>>>(oat, w_out, b_out, (float*)d_out);
}

// Round 3
// 133.288 us; speedup vs baseline: 1.9422x; 1.5956x over previous
//
#include <hip/hip_runtime.h>
#include <hip/hip_bf16.h>

#define NQ     4000
#define DMODEL 256
#define NHEAD  8
#define NLVL   4
#define NPT    4
#define DHEAD  32
#define LENIN  37440
#define NOFF   384
#define NATT   128
#define NPROJ  512   // NOFF + NATT

typedef _Float16 f16x8 __attribute__((ext_vector_type(8)));
typedef float    f32x4 __attribute__((ext_vector_type(4)));

// --------------------------------------------- w_value cast+transpose (tiny)
// WT[n][k] = (f16) W[k][n].  64x64 LDS tiles, grid (4,4), 256 threads.
__global__ __launch_bounds__(256) void cast_transpose(
    const float* __restrict__ W, _Float16* __restrict__ WT)
{
    __shared__ float t[64][65];
    const int tid = threadIdx.x;
    const int bx = blockIdx.x * 64;   // n-range
    const int by = blockIdx.y * 64;   // k-range
    const int c = tid & 63, r0 = tid >> 6;
    #pragma unroll
    for (int i = 0; i < 16; ++i) {
        int r = r0 + i * 4;
        t[r][c] = W[(size_t)(by + r) * DMODEL + bx + c];
    }
    __syncthreads();
    #pragma unroll
    for (int i = 0; i < 16; ++i) {
        int n = r0 + i * 4;
        WT[(size_t)(bx + n) * DMODEL + by + c] = (_Float16)t[c][n];
    }
}

// ---------------------------------------------------- value GEMM (f16 MFMA)
// C_f16[LENIN,256] = A_f32[LENIN,256] @ WT^T + bias.  BM=64, BN=256, BK=32.
// 256 threads = 4 waves; wave w owns cols [64w,64w+64); 4x4 16x16 frags.
#define VBK 32
#define LDH 40   // padded LDS row (halfs): 80B stride -> ~2-way conflicts only

__global__ __launch_bounds__(256) void gemm_value_mfma(
    const float* __restrict__ A, const _Float16* __restrict__ BT,
    const float* __restrict__ bias, _Float16* __restrict__ C)
{
    __shared__ __align__(16) _Float16 As[64][LDH];
    __shared__ __align__(16) _Float16 Bs[256][LDH];
    const int tid  = threadIdx.x;
    const int wave = tid >> 6, lane = tid & 63;
    const int brow = blockIdx.x * 64;
    const int l15 = lane & 15, l16 = lane >> 4;

    f32x4 acc[4][4] = {};   // [mi][ni]

    for (int k0 = 0; k0 < DMODEL; k0 += VBK) {
        {   // stage A: 64 rows x 32 k fp32 -> f16 (8 f32 per thread)
            int row = tid >> 2, kq = (tid & 3) * 8;
            const float* src = &A[(size_t)(brow + row) * DMODEL + k0 + kq];
            float4 v0 = *(const float4*)src;
            float4 v1 = *(const float4*)(src + 4);
            f16x8 h;
            h[0] = (_Float16)v0.x; h[1] = (_Float16)v0.y;
            h[2] = (_Float16)v0.z; h[3] = (_Float16)v0.w;
            h[4] = (_Float16)v1.x; h[5] = (_Float16)v1.y;
            h[6] = (_Float16)v1.z; h[7] = (_Float16)v1.w;
            *(f16x8*)&As[row][kq] = h;
        }
        {   // stage B: 256 n x 32 k f16 (4 x 16B chunks per thread)
            #pragma unroll
            for (int j = 0; j < 4; ++j) {
                int id = tid + 256 * j;       // chunk id = n*4 + kc
                int n = id >> 2, kc = id & 3;
                f16x8 v = *(const f16x8*)&BT[(size_t)n * DMODEL + k0 + kc * 8];
                *(f16x8*)&Bs[n][kc * 8] = v;
            }
        }
        __syncthreads();
        f16x8 af[4], bf[4];
        #pragma unroll
        for (int mi = 0; mi < 4; ++mi)
            af[mi] = *(const f16x8*)&As[mi * 16 + l15][l16 * 8];
        #pragma unroll
        for (int ni = 0; ni < 4; ++ni)
            bf[ni] = *(const f16x8*)&Bs[wave * 64 + ni * 16 + l15][l16 * 8];
        #pragma unroll
        for (int mi = 0; mi < 4; ++mi)
            #pragma unroll
            for (int ni = 0; ni < 4; ++ni)
                acc[mi][ni] = __builtin_amdgcn_mfma_f32_16x16x32_f16(
                    af[mi], bf[ni], acc[mi][ni], 0, 0, 0);
        __syncthreads();
    }

    #pragma unroll
    for (int ni = 0; ni < 4; ++ni) {
        int col = wave * 64 + ni * 16 + l15;
        float b = bias[col];
        #pragma unroll
        for (int mi = 0; mi < 4; ++mi)
            #pragma unroll
            for (int j = 0; j < 4; ++j) {
                int row = brow + mi * 16 + l16 * 4 + j;
                C[(size_t)row * DMODEL + col] = (_Float16)(acc[mi][ni][j] + b);
            }
    }
}

// ------------------------------------------------- off+attn projection GEMM
#define BM 64
#define BN 64
#define BK 16

__global__ __launch_bounds__(256) void gemm_offattn(
    const float* __restrict__ A,
    const float* __restrict__ Woff, const float* __restrict__ Boff,
    const float* __restrict__ Watt, const float* __restrict__ Batt,
    float* __restrict__ C)
{
    __shared__ float As[BK][BM];
    __shared__ float Bs[BK][BN];
    const int tid  = threadIdx.x;
    const int brow = blockIdx.y * BM;
    const int bcol = blockIdx.x * BN;
    const int ty = tid >> 4, tx = tid & 15;

    const bool is_off = (bcol < NOFF);
    const float* B    = is_off ? Woff : Watt;
    const float* bias = is_off ? Boff : Batt;
    const int    ldb  = is_off ? NOFF : NATT;
    const int    cb   = is_off ? bcol : bcol - NOFF;

    float acc[4][4] = {};

    for (int k0 = 0; k0 < DMODEL; k0 += BK) {
        {
            int row = tid >> 2, kq = (tid & 3) * 4;
            int rg  = brow + row; if (rg >= NQ) rg = NQ - 1;
            float4 av = *(const float4*)&A[(size_t)rg * DMODEL + k0 + kq];
            As[kq + 0][row] = av.x;
            As[kq + 1][row] = av.y;
            As[kq + 2][row] = av.z;
            As[kq + 3][row] = av.w;
        }
        {
            int kk = tid >> 4, col = (tid & 15) * 4;
            *(float4*)&Bs[kk][col] = *(const float4*)&B[(size_t)(k0 + kk) * ldb + cb + col];
        }
        __syncthreads();
        #pragma unroll
        for (int kk = 0; kk < BK; ++kk) {
            float a[4], b[4];
            *(float4*)a = *(const float4*)&As[kk][ty * 4];
            *(float4*)b = *(const float4*)&Bs[kk][tx * 4];
            #pragma unroll
            for (int i = 0; i < 4; ++i)
                #pragma unroll
                for (int j = 0; j < 4; ++j)
                    acc[i][j] += a[i] * b[j];
        }
        __syncthreads();
    }

    float4 bv = *(const float4*)&bias[cb + tx * 4];
    #pragma unroll
    for (int i = 0; i < 4; ++i) {
        int r = brow + ty * 4 + i;
        if (r < NQ) {
            float4 v;
            v.x = acc[i][0] + bv.x;
            v.y = acc[i][1] + bv.y;
            v.z = acc[i][2] + bv.z;
            v.w = acc[i][3] + bv.w;
            *(float4*)&C[(size_t)r * NPROJ + bcol + tx * 4] = v;
        }
    }
}

// -------------------------- fused: loc + softmax + trilinear sample (per q)
__global__ __launch_bounds__(256) void sample_fused(
    const _Float16* __restrict__ value, const float* __restrict__ proj,
    const float* __restrict__ refpts, float* __restrict__ oat)
{
    __shared__ float loc_s[NOFF];
    __shared__ float aw_s[NATT];
    const int q = blockIdx.x;
    const int tid = threadIdx.x;

    const float p0 = proj[(size_t)q * NPROJ + tid];
    const float p1 = proj[(size_t)q * NPROJ + 256 + tid];

    {   // t = tid (0..255): offset columns
        int t2 = tid / 3, lvl = (t2 / NPT) & 3, c = tid - t2 * 3;
        float norm = (float)(32 >> lvl);
        loc_s[tid] = refpts[((size_t)q * NLVL + lvl) * 3 + c] + p0 / norm;
    }
    if (tid < 128) {   // t = 256+tid (256..383): offset columns (waves 0,1)
        int t = 256 + tid;
        int t2 = t / 3, lvl = (t2 / NPT) & 3, c = t - t2 * 3;
        float norm = (float)(32 >> lvl);
        loc_s[t] = refpts[((size_t)q * NLVL + lvl) * 3 + c] + p1 / norm;
    } else {           // t = 384..511: attn columns (waves 2,3), softmax/16
        int c = tid - 128;                 // h*16 + (lvl*4+p)
        float m = p1;
        #pragma unroll
        for (int o = 8; o >= 1; o >>= 1) m = fmaxf(m, __shfl_xor(m, o, 16));
        float e = expf(p1 - m);
        float s = e;
        #pragma unroll
        for (int o = 8; o >= 1; o >>= 1) s += __shfl_xor(s, o, 16);
        aw_s[c] = e / s;
    }
    __syncthreads();

    const int h = tid >> 5, d = tid & 31;
    const int DIMS[4]  = {32, 16, 8, 4};
    const int START[4] = {0, 32768, 36864, 37376};
    const float* locq = loc_s + h * 48;
    const float* awq  = aw_s  + h * 16;

    float acc = 0.f;
    #pragma unroll
    for (int lvl = 0; lvl < 4; ++lvl) {
        const int   S    = DIMS[lvl];
        const float Sf   = (float)S;
        const int   base = START[lvl];
        #pragma unroll
        for (int p = 0; p < 4; ++p) {
            float lx = locq[(lvl * 4 + p) * 3 + 0];
            float ly = locq[(lvl * 4 + p) * 3 + 1];
            float lz = locq[(lvl * 4 + p) * 3 + 2];
            float aw = awq[lvl * 4 + p];
            float x = lx * Sf - 0.5f, y = ly * Sf - 0.5f, z = lz * Sf - 0.5f;
            float x0f = floorf(x), y0f = floorf(y), z0f = floorf(z);
            float fx = x - x0f, fy = y - y0f, fz = z - z0f;
            int x0 = (int)x0f, y0 = (int)y0f, z0 = (int)z0f;
            #pragma unroll
            for (int dz = 0; dz < 2; ++dz) {
                float wz = dz ? fz : 1.f - fz; int zi = z0 + dz;
                #pragma unroll
                for (int dy = 0; dy < 2; ++dy) {
                    float wy = dy ? fy : 1.f - fy; int yi = y0 + dy;
                    #pragma unroll
                    for (int dx = 0; dx < 2; ++dx) {
                        float wx = dx ? fx : 1.f - fx; int xi = x0 + dx;
                        if ((unsigned)xi < (unsigned)S &&
                            (unsigned)yi < (unsigned)S &&
                            (unsigned)zi < (unsigned)S) {
                            float cw  = wx * wy * wz * aw;
                            int   idx = (zi * S + yi) * S + xi;
                            acc += cw * (float)value[(size_t)(base + idx) * DMODEL + h * DHEAD + d];
                        }
                    }
                }
            }
        }
    }
    oat[(size_t)q * DMODEL + h * DHEAD + d] = acc;
}

// ----------------------------------------- output projection (fp32, tiled)
__global__ __launch_bounds__(256) void out_gemm_t(
    const float* __restrict__ A, const float* __restrict__ B,
    const float* __restrict__ bias, float* __restrict__ C)
{
    __shared__ float As[BK][BM];
    __shared__ float Bs[BK][BN];
    const int tid  = threadIdx.x;
    const int brow = blockIdx.y * BM;
    const int bcol = blockIdx.x * BN;
    const int ty = tid >> 4, tx = tid & 15;

    float acc[4][4] = {};

    for (int k0 = 0; k0 < DMODEL; k0 += BK) {
        {
            int row = tid >> 2, kq = (tid & 3) * 4;
            int rg  = brow + row; if (rg >= NQ) rg = NQ - 1;
            float4 av = *(const float4*)&A[(size_t)rg * DMODEL + k0 + kq];
            As[kq + 0][row] = av.x;
            As[kq + 1][row] = av.y;
            As[kq + 2][row] = av.z;
            As[kq + 3][row] = av.w;
        }
        {
            int kk = tid >> 4, col = (tid & 15) * 4;
            *(float4*)&Bs[kk][col] = *(const float4*)&B[(size_t)(k0 + kk) * DMODEL + bcol + col];
        }
        __syncthreads();
        #pragma unroll
        for (int kk = 0; kk < BK; ++kk) {
            float a[4], b[4];
            *(float4*)a = *(const float4*)&As[kk][ty * 4];
            *(float4*)b = *(const float4*)&Bs[kk][tx * 4];
            #pragma unroll
            for (int i = 0; i < 4; ++i)
                #pragma unroll
                for (int j = 0; j < 4; ++j)
                    acc[i][j] += a[i] * b[j];
        }
        __syncthreads();
    }

    float4 bv = *(const float4*)&bias[bcol + tx * 4];
    #pragma unroll
    for (int i = 0; i < 4; ++i) {
        int r = brow + ty * 4 + i;
        if (r < NQ) {
            float4 v;
            v.x = acc[i][0] + bv.x;
            v.y = acc[i][1] + bv.y;
            v.z = acc[i][2] + bv.z;
            v.w = acc[i][3] + bv.w;
            *(float4*)&C[(size_t)r * DMODEL + bcol + tx * 4] = v;
        }
    }
}

extern "C" void kernel_launch(void* const* d_in, const int* in_sizes, int n_in,
                              void* d_out, int out_size, void* d_ws, size_t ws_size,
                              hipStream_t stream) {
    const float* query         = (const float*)d_in[0];
    const float* refpts        = (const float*)d_in[1];
    const float* input_flatten = (const float*)d_in[2];
    const float* w_value       = (const float*)d_in[3];
    const float* b_value       = (const float*)d_in[4];
    const float* w_off         = (const float*)d_in[5];
    const float* b_off         = (const float*)d_in[6];
    const float* w_attn        = (const float*)d_in[7];
    const float* b_attn        = (const float*)d_in[8];
    const float* w_out         = (const float*)d_in[9];
    const float* b_out         = (const float*)d_in[10];

    _Float16* valueH = (_Float16*)d_ws;                       // 19,169,280 B
    _Float16* wT     = valueH + (size_t)LENIN * DMODEL;       //    131,072 B
    float*    proj   = (float*)(wT + (size_t)DMODEL * DMODEL);//  8,192,000 B
    float*    oat    = proj + (size_t)NQ * NPROJ;             //  4,096,000 B
    // total ~31.6 MB of workspace

    cast_transpose<<<dim3(4, 4), 256, 0, stream>>>(w_value, wT);
    gemm_value_mfma<<<LENIN / 64, 256, 0, stream>>>(input_flatten, wT, b_value, valueH);
    dim3 g2(NPROJ / BN, (NQ + BM - 1) / BM);
    gemm_offattn<<<g2, 256, 0, stream>>>(query, w_off, b_off, w_attn, b_attn, proj);
    sample_fused<<<NQ, 256, 0, stream>>>(valueH, proj, refpts, oat);
    dim3 g3(DMODEL / BN, (NQ + BM - 1) / BM);
    out_gemm_t<<<g3, 256, 0, stream>>>(oat, w_out, b_out, (float*)d_out);
}

// Round 4
// 88.335 us; speedup vs baseline: 2.9306x; 1.5089x over previous
//
#include <hip/hip_runtime.h>
#include <hip/hip_bf16.h>

#define NQ     4000
#define DMODEL 256
#define NHEAD  8
#define NLVL   4
#define NPT    4
#define DHEAD  32
#define LENIN  37440
#define NOFF   384
#define NATT   128
#define NPROJ  512   // NOFF + NATT

typedef _Float16 f16x8 __attribute__((ext_vector_type(8)));
typedef _Float16 f16x4 __attribute__((ext_vector_type(4)));
typedef float    f32x4 __attribute__((ext_vector_type(4)));

// ------------------------------------- all weight casts+transposes, 1 launch
// Produces WT[n][k] = (f16) W[k][n] for w_value, [w_off|w_attn] (cat), w_out.
// grid (16, 4), 256 threads. xt: 0-3 value, 4-9 off, 10-11 attn, 12-15 out.
__global__ __launch_bounds__(256) void cast_transpose_all(
    const float* __restrict__ wv, const float* __restrict__ wo,
    const float* __restrict__ wa, const float* __restrict__ wu,
    _Float16* __restrict__ wvT, _Float16* __restrict__ catT,
    _Float16* __restrict__ wuT)
{
    __shared__ float t[64][65];
    const int xt = blockIdx.x, kt = blockIdx.y;
    const float* W; _Float16* WT; int ncols, col0, nbase;
    if (xt < 4)       { W = wv; WT = wvT;  ncols = 256; col0 = xt * 64;        nbase = col0; }
    else if (xt < 10) { W = wo; WT = catT; ncols = 384; col0 = (xt - 4) * 64;  nbase = col0; }
    else if (xt < 12) { W = wa; WT = catT; ncols = 128; col0 = (xt - 10) * 64; nbase = 384 + col0; }
    else              { W = wu; WT = wuT;  ncols = 256; col0 = (xt - 12) * 64; nbase = col0; }

    const int by = kt * 64;           // k-range
    const int tid = threadIdx.x;
    const int c = tid & 63, r0 = tid >> 6;
    #pragma unroll
    for (int i = 0; i < 16; ++i) {
        int r = r0 + i * 4;
        t[r][c] = W[(size_t)(by + r) * ncols + col0 + c];
    }
    __syncthreads();
    #pragma unroll
    for (int i = 0; i < 16; ++i) {
        int n = r0 + i * 4;
        WT[(size_t)(nbase + n) * DMODEL + by + c] = (_Float16)t[c][n];
    }
}

// ------------------------------------------------- generic f16 MFMA GEMM
// C[M,*] = A_f32[M,256] @ BT_f16[N,256]^T + bias.  64 rows x 256 cols / block.
// blockIdx.x = row tile, blockIdx.y = 256-col block. 256 threads = 4 waves.
#define LDH 40   // padded LDS row (halfs)

template <typename OutT>
__global__ __launch_bounds__(256) void gemm_mfma(
    const float* __restrict__ A, const _Float16* __restrict__ BT,
    const float* __restrict__ bias0, const float* __restrict__ bias1,
    int split, OutT* __restrict__ C, int M, int ldc)
{
    __shared__ __align__(16) _Float16 As[64][LDH];
    __shared__ __align__(16) _Float16 Bs[256][LDH];
    const int tid  = threadIdx.x;
    const int wave = tid >> 6, lane = tid & 63;
    const int brow = blockIdx.x * 64;
    const int ncb  = blockIdx.y * 256;
    const int l15 = lane & 15, l16 = lane >> 4;

    f32x4 acc[4][4] = {};   // [mi][ni]

    for (int k0 = 0; k0 < DMODEL; k0 += 32) {
        {   // stage A: 64 rows x 32 k fp32 -> f16
            int row = tid >> 2, kq = (tid & 3) * 8;
            int rg = brow + row; if (rg >= M) rg = M - 1;
            const float* src = &A[(size_t)rg * DMODEL + k0 + kq];
            float4 v0 = *(const float4*)src;
            float4 v1 = *(const float4*)(src + 4);
            f16x8 h;
            h[0] = (_Float16)v0.x; h[1] = (_Float16)v0.y;
            h[2] = (_Float16)v0.z; h[3] = (_Float16)v0.w;
            h[4] = (_Float16)v1.x; h[5] = (_Float16)v1.y;
            h[6] = (_Float16)v1.z; h[7] = (_Float16)v1.w;
            *(f16x8*)&As[row][kq] = h;
        }
        {   // stage B: 256 n x 32 k f16
            #pragma unroll
            for (int j = 0; j < 4; ++j) {
                int id = tid + 256 * j;       // chunk id = n*4 + kc
                int n = id >> 2, kc = id & 3;
                f16x8 v = *(const f16x8*)&BT[(size_t)(ncb + n) * DMODEL + k0 + kc * 8];
                *(f16x8*)&Bs[n][kc * 8] = v;
            }
        }
        __syncthreads();
        f16x8 af[4], bf[4];
        #pragma unroll
        for (int mi = 0; mi < 4; ++mi)
            af[mi] = *(const f16x8*)&As[mi * 16 + l15][l16 * 8];
        #pragma unroll
        for (int ni = 0; ni < 4; ++ni)
            bf[ni] = *(const f16x8*)&Bs[wave * 64 + ni * 16 + l15][l16 * 8];
        #pragma unroll
        for (int mi = 0; mi < 4; ++mi)
            #pragma unroll
            for (int ni = 0; ni < 4; ++ni)
                acc[mi][ni] = __builtin_amdgcn_mfma_f32_16x16x32_f16(
                    af[mi], bf[ni], acc[mi][ni], 0, 0, 0);
        __syncthreads();
    }

    #pragma unroll
    for (int ni = 0; ni < 4; ++ni) {
        int col = ncb + wave * 64 + ni * 16 + l15;
        float b = (col < split) ? bias0[col] : bias1[col - split];
        #pragma unroll
        for (int mi = 0; mi < 4; ++mi)
            #pragma unroll
            for (int j = 0; j < 4; ++j) {
                int row = brow + mi * 16 + l16 * 4 + j;
                if (row < M)
                    C[(size_t)row * ldc + col] = (OutT)(acc[mi][ni][j] + b);
            }
    }
}

// ---------------- fused: loc + softmax + corner precompute + gather (4 q/blk)
// One wave per query. Phase 0: proj->loc/attn. Phase 1: 1024 (h,pt,corner)
// -> (byte addr, weight) in LDS. Phase 2: lane=(h,do8) gathers 4 channels.
__global__ __launch_bounds__(256) void sample_fused2(
    const _Float16* __restrict__ value, const float* __restrict__ proj,
    const float* __restrict__ refpts, float* __restrict__ oat)
{
    __shared__ float loc_s[4][NOFF];
    __shared__ float aw_s[4][NATT];
    __shared__ uint2 cw_s[4][1056];     // [h*132 + pt*8 + c]

    const int tid  = threadIdx.x;
    const int wv   = tid >> 6, lane = tid & 63;
    const int q    = blockIdx.x * 4 + wv;
    const float* pq = proj + (size_t)q * NPROJ;

    // ---- phase 0: locations + softmax
    #pragma unroll
    for (int i = 0; i < 8; ++i) {
        int t = i * 64 + lane;
        float v = pq[t];
        if (t < NOFF) {
            int t2 = t / 3, lvl = (t2 >> 2) & 3, c = t - t2 * 3;
            float norm = (float)(32 >> lvl);
            loc_s[wv][t] = refpts[((size_t)q * NLVL + lvl) * 3 + c] + v / norm;
        } else {
            float m = v;
            #pragma unroll
            for (int o = 8; o >= 1; o >>= 1) m = fmaxf(m, __shfl_xor(m, o, 16));
            float e = expf(v - m);
            float s = e;
            #pragma unroll
            for (int o = 8; o >= 1; o >>= 1) s += __shfl_xor(s, o, 16);
            aw_s[wv][t - NOFF] = e / s;
        }
    }
    __syncthreads();

    // ---- phase 1: per-corner address + weight
    #pragma unroll
    for (int i = 0; i < 16; ++i) {
        int id = i * 64 + lane;            // h*128 + pt*8 + c
        int h = id >> 7, pt = (id >> 3) & 15, c = id & 7;
        int lvl = pt >> 2;
        int S = 32 >> lvl;
        float Sf = (float)S;
        int base = (lvl == 0) ? 0 : (lvl == 1) ? 32768 : (lvl == 2) ? 36864 : 37376;

        float lx = loc_s[wv][h * 48 + pt * 3 + 0];
        float ly = loc_s[wv][h * 48 + pt * 3 + 1];
        float lz = loc_s[wv][h * 48 + pt * 3 + 2];
        float aw = aw_s[wv][h * 16 + pt];

        float x = lx * Sf - 0.5f, y = ly * Sf - 0.5f, z = lz * Sf - 0.5f;
        float x0f = floorf(x), y0f = floorf(y), z0f = floorf(z);
        float fx = x - x0f, fy = y - y0f, fz = z - z0f;
        int dx = c & 1, dy = (c >> 1) & 1, dz = c >> 2;
        int xi = (int)x0f + dx, yi = (int)y0f + dy, zi = (int)z0f + dz;
        float wx = dx ? fx : 1.f - fx;
        float wy = dy ? fy : 1.f - fy;
        float wz = dz ? fz : 1.f - fz;
        bool valid = (unsigned)xi < (unsigned)S &&
                     (unsigned)yi < (unsigned)S &&
                     (unsigned)zi < (unsigned)S;
        float w = valid ? wx * wy * wz * aw : 0.f;
        int xc = min(max(xi, 0), S - 1);
        int yc = min(max(yi, 0), S - 1);
        int zc = min(max(zi, 0), S - 1);
        int idx = (zc * S + yc) * S + xc;
        unsigned addr = (unsigned)(base + idx) * 512u + (unsigned)h * 64u;  // bytes
        cw_s[wv][h * 132 + pt * 8 + c] = make_uint2(addr, __float_as_uint(w));
    }
    __syncthreads();

    // ---- phase 2: gather. lane = h(3b) | do8(3b): 8 lanes x 4 ch per head.
    const int h = lane >> 3, do8 = lane & 7;
    const char* vb = (const char*)value + do8 * 8;
    const uint2* cw = &cw_s[wv][h * 132];

    float acc0 = 0.f, acc1 = 0.f, acc2 = 0.f, acc3 = 0.f;
    #pragma unroll 4
    for (int pt = 0; pt < 16; ++pt) {
        #pragma unroll
        for (int c = 0; c < 8; ++c) {
            uint2 cwv = cw[pt * 8 + c];
            float w = __uint_as_float(cwv.y);
            f16x4 v = *(const f16x4*)(vb + cwv.x);
            acc0 += w * (float)v[0];
            acc1 += w * (float)v[1];
            acc2 += w * (float)v[2];
            acc3 += w * (float)v[3];
        }
    }
    float4 r = make_float4(acc0, acc1, acc2, acc3);
    *(float4*)&oat[(size_t)q * DMODEL + h * DHEAD + do8 * 4] = r;
}

extern "C" void kernel_launch(void* const* d_in, const int* in_sizes, int n_in,
                              void* d_out, int out_size, void* d_ws, size_t ws_size,
                              hipStream_t stream) {
    const float* query         = (const float*)d_in[0];
    const float* refpts        = (const float*)d_in[1];
    const float* input_flatten = (const float*)d_in[2];
    const float* w_value       = (const float*)d_in[3];
    const float* b_value       = (const float*)d_in[4];
    const float* w_off         = (const float*)d_in[5];
    const float* b_off         = (const float*)d_in[6];
    const float* w_attn        = (const float*)d_in[7];
    const float* b_attn        = (const float*)d_in[8];
    const float* w_out         = (const float*)d_in[9];
    const float* b_out         = (const float*)d_in[10];

    _Float16* valueH = (_Float16*)d_ws;                    // 9,584,640 halfs
    _Float16* wvT    = valueH + (size_t)LENIN * DMODEL;    //    65,536
    _Float16* catT   = wvT + 256 * 256;                    //   131,072
    _Float16* wuT    = catT + 512 * 256;                   //    65,536
    float*    proj   = (float*)(wuT + 256 * 256);          // 2,048,000 floats
    float*    oat    = proj + (size_t)NQ * NPROJ;          // 1,024,000 floats
    // total ~32 MB of workspace

    cast_transpose_all<<<dim3(16, 4), 256, 0, stream>>>(
        w_value, w_off, w_attn, w_out, wvT, catT, wuT);

    gemm_mfma<_Float16><<<dim3(LENIN / 64, 1), 256, 0, stream>>>(
        input_flatten, wvT, b_value, b_value, 256, valueH, LENIN, DMODEL);

    gemm_mfma<float><<<dim3((NQ + 63) / 64, 2), 256, 0, stream>>>(
        query, catT, b_off, b_attn, NOFF, proj, NQ, NPROJ);

    sample_fused2<<<NQ / 4, 256, 0, stream>>>(valueH, proj, refpts, oat);

    gemm_mfma<float><<<dim3((NQ + 63) / 64, 1), 256, 0, stream>>>(
        oat, wuT, b_out, b_out, 256, (float*)d_out, NQ, DMODEL);
}

// Round 5
// 85.050 us; speedup vs baseline: 3.0437x; 1.0386x over previous
//
#include <hip/hip_runtime.h>
#include <hip/hip_bf16.h>

#define NQ     4000
#define DMODEL 256
#define NHEAD  8
#define NLVL   4
#define NPT    4
#define DHEAD  32
#define LENIN  37440
#define NOFF   384
#define NATT   128
#define NPROJ  512   // NOFF + NATT

typedef _Float16 f16x8 __attribute__((ext_vector_type(8)));
typedef _Float16 f16x4 __attribute__((ext_vector_type(4)));
typedef float    f32x4 __attribute__((ext_vector_type(4)));

// ------------------------------------- all weight casts+transposes, 1 launch
// Produces WT[n][k] = (f16) W[k][n] for w_value, [w_off|w_attn] (cat), w_out.
// grid (16, 4), 256 threads. xt: 0-3 value, 4-9 off, 10-11 attn, 12-15 out.
__global__ __launch_bounds__(256) void cast_transpose_all(
    const float* __restrict__ wv, const float* __restrict__ wo,
    const float* __restrict__ wa, const float* __restrict__ wu,
    _Float16* __restrict__ wvT, _Float16* __restrict__ catT,
    _Float16* __restrict__ wuT)
{
    __shared__ float t[64][65];
    const int xt = blockIdx.x, kt = blockIdx.y;
    const float* W; _Float16* WT; int ncols, col0, nbase;
    if (xt < 4)       { W = wv; WT = wvT;  ncols = 256; col0 = xt * 64;        nbase = col0; }
    else if (xt < 10) { W = wo; WT = catT; ncols = 384; col0 = (xt - 4) * 64;  nbase = col0; }
    else if (xt < 12) { W = wa; WT = catT; ncols = 128; col0 = (xt - 10) * 64; nbase = 384 + col0; }
    else              { W = wu; WT = wuT;  ncols = 256; col0 = (xt - 12) * 64; nbase = col0; }

    const int by = kt * 64;           // k-range
    const int tid = threadIdx.x;
    const int c = tid & 63, r0 = tid >> 6;
    #pragma unroll
    for (int i = 0; i < 16; ++i) {
        int r = r0 + i * 4;
        t[r][c] = W[(size_t)(by + r) * ncols + col0 + c];
    }
    __syncthreads();
    #pragma unroll
    for (int i = 0; i < 16; ++i) {
        int n = r0 + i * 4;
        WT[(size_t)(nbase + n) * DMODEL + by + c] = (_Float16)t[c][n];
    }
}

// ------------------------------------------------- generic f16 MFMA GEMM
// C = A[M,256] @ BT[N,256]^T + bias.  64 rows x 256 cols per block.
// InT: float (cast to f16 in staging) or _Float16. HM: head-major f16 output
// C[((col>>5)*LENIN + row)*32 + (col&31)]. Register double-buffered staging.
#define LDH 40   // padded LDS row (halfs)

template <typename InT, typename OutT, bool HM>
__global__ __launch_bounds__(256) void gemm_mfma(
    const InT* __restrict__ A, const _Float16* __restrict__ BT,
    const float* __restrict__ bias0, const float* __restrict__ bias1,
    int split, OutT* __restrict__ C, int M, int ldc)
{
    __shared__ __align__(16) _Float16 As[64][LDH];
    __shared__ __align__(16) _Float16 Bs[256][LDH];
    const int tid  = threadIdx.x;
    const int wave = tid >> 6, lane = tid & 63;
    const int brow = blockIdx.x * 64;
    const int ncb  = blockIdx.y * 256;
    const int l15 = lane & 15, l16 = lane >> 4;

    const int arow = tid >> 2, akq = (tid & 3) * 8;
    int arg = brow + arow; if (arg >= M) arg = M - 1;
    const InT* aptr = A + (size_t)arg * DMODEL + akq;

    const _Float16* bptr[4];
    int bn[4], bkc[4];
    #pragma unroll
    for (int j = 0; j < 4; ++j) {
        int id = tid + 256 * j;            // chunk id = n*4 + kc
        bn[j] = id >> 2; bkc[j] = (id & 3) * 8;
        bptr[j] = BT + (size_t)(ncb + bn[j]) * DMODEL + bkc[j];
    }

    f32x4 acc[4][4] = {};   // [mi][ni]
    float4 a0, a1; f16x8 ah;
    f16x8 bh[4];

    // prefetch K-step 0
    if constexpr (sizeof(InT) == 2) {
        ah = *(const f16x8*)(const void*)aptr;
    } else {
        a0 = *(const float4*)(const void*)aptr;
        a1 = *(const float4*)(const void*)(aptr + 4);
    }
    #pragma unroll
    for (int j = 0; j < 4; ++j) bh[j] = *(const f16x8*)bptr[j];

    for (int k0 = 0; k0 < DMODEL; k0 += 32) {
        // write staged registers to LDS
        if constexpr (sizeof(InT) == 2) {
            *(f16x8*)&As[arow][akq] = ah;
        } else {
            f16x8 h;
            h[0] = (_Float16)a0.x; h[1] = (_Float16)a0.y;
            h[2] = (_Float16)a0.z; h[3] = (_Float16)a0.w;
            h[4] = (_Float16)a1.x; h[5] = (_Float16)a1.y;
            h[6] = (_Float16)a1.z; h[7] = (_Float16)a1.w;
            *(f16x8*)&As[arow][akq] = h;
        }
        #pragma unroll
        for (int j = 0; j < 4; ++j) *(f16x8*)&Bs[bn[j]][bkc[j]] = bh[j];
        __syncthreads();

        // issue next K-step's global loads before the MFMA cluster
        if (k0 + 32 < DMODEL) {
            if constexpr (sizeof(InT) == 2) {
                ah = *(const f16x8*)(const void*)(aptr + k0 + 32);
            } else {
                a0 = *(const float4*)(const void*)(aptr + k0 + 32);
                a1 = *(const float4*)(const void*)(aptr + k0 + 36);
            }
            #pragma unroll
            for (int j = 0; j < 4; ++j) bh[j] = *(const f16x8*)(bptr[j] + k0 + 32);
        }

        f16x8 af[4], bf[4];
        #pragma unroll
        for (int mi = 0; mi < 4; ++mi)
            af[mi] = *(const f16x8*)&As[mi * 16 + l15][l16 * 8];
        #pragma unroll
        for (int ni = 0; ni < 4; ++ni)
            bf[ni] = *(const f16x8*)&Bs[wave * 64 + ni * 16 + l15][l16 * 8];
        #pragma unroll
        for (int mi = 0; mi < 4; ++mi)
            #pragma unroll
            for (int ni = 0; ni < 4; ++ni)
                acc[mi][ni] = __builtin_amdgcn_mfma_f32_16x16x32_f16(
                    af[mi], bf[ni], acc[mi][ni], 0, 0, 0);
        __syncthreads();
    }

    #pragma unroll
    for (int ni = 0; ni < 4; ++ni) {
        int col = ncb + wave * 64 + ni * 16 + l15;
        float b = (col < split) ? bias0[col] : bias1[col - split];
        #pragma unroll
        for (int mi = 0; mi < 4; ++mi)
            #pragma unroll
            for (int j = 0; j < 4; ++j) {
                int row = brow + mi * 16 + l16 * 4 + j;
                if (row < M) {
                    float v = acc[mi][ni][j] + b;
                    if constexpr (HM) {
                        int h = col >> 5, d = col & 31;
                        C[((size_t)h * LENIN + row) * DHEAD + d] = (OutT)v;
                    } else {
                        C[(size_t)row * ldc + col] = (OutT)v;
                    }
                }
            }
    }
}

// ---------------- fused: loc + softmax + corner precompute + gather (4 q/blk)
// One wave per query. value is head-major: [h][cell][32ch] f16.
__global__ __launch_bounds__(256) void sample_fused2(
    const _Float16* __restrict__ value, const float* __restrict__ proj,
    const float* __restrict__ refpts, _Float16* __restrict__ oat)
{
    __shared__ float loc_s[4][NOFF];
    __shared__ float aw_s[4][NATT];
    __shared__ uint2 cw_s[4][1056];     // [h*132 + pt*8 + c]

    const int tid  = threadIdx.x;
    const int wv   = tid >> 6, lane = tid & 63;
    const int q    = blockIdx.x * 4 + wv;
    const float* pq = proj + (size_t)q * NPROJ;

    // ---- phase 0: locations + softmax
    #pragma unroll
    for (int i = 0; i < 8; ++i) {
        int t = i * 64 + lane;
        float v = pq[t];
        if (t < NOFF) {
            int t2 = t / 3, lvl = (t2 >> 2) & 3, c = t - t2 * 3;
            float norm = (float)(32 >> lvl);
            loc_s[wv][t] = refpts[((size_t)q * NLVL + lvl) * 3 + c] + v / norm;
        } else {
            float m = v;
            #pragma unroll
            for (int o = 8; o >= 1; o >>= 1) m = fmaxf(m, __shfl_xor(m, o, 16));
            float e = expf(v - m);
            float s = e;
            #pragma unroll
            for (int o = 8; o >= 1; o >>= 1) s += __shfl_xor(s, o, 16);
            aw_s[wv][t - NOFF] = e / s;
        }
    }
    __syncthreads();

    // ---- phase 1: per-corner byte address (head-major) + weight
    #pragma unroll
    for (int i = 0; i < 16; ++i) {
        int id = i * 64 + lane;            // h*128 + pt*8 + c
        int h = id >> 7, pt = (id >> 3) & 15, c = id & 7;
        int lvl = pt >> 2;
        int S = 32 >> lvl;
        float Sf = (float)S;
        int base = (lvl == 0) ? 0 : (lvl == 1) ? 32768 : (lvl == 2) ? 36864 : 37376;

        float lx = loc_s[wv][h * 48 + pt * 3 + 0];
        float ly = loc_s[wv][h * 48 + pt * 3 + 1];
        float lz = loc_s[wv][h * 48 + pt * 3 + 2];
        float aw = aw_s[wv][h * 16 + pt];

        float x = lx * Sf - 0.5f, y = ly * Sf - 0.5f, z = lz * Sf - 0.5f;
        float x0f = floorf(x), y0f = floorf(y), z0f = floorf(z);
        float fx = x - x0f, fy = y - y0f, fz = z - z0f;
        int dx = c & 1, dy = (c >> 1) & 1, dz = c >> 2;
        int xi = (int)x0f + dx, yi = (int)y0f + dy, zi = (int)z0f + dz;
        float wx = dx ? fx : 1.f - fx;
        float wy = dy ? fy : 1.f - fy;
        float wz = dz ? fz : 1.f - fz;
        bool valid = (unsigned)xi < (unsigned)S &&
                     (unsigned)yi < (unsigned)S &&
                     (unsigned)zi < (unsigned)S;
        float w = valid ? wx * wy * wz * aw : 0.f;
        int xc = min(max(xi, 0), S - 1);
        int yc = min(max(yi, 0), S - 1);
        int zc = min(max(zi, 0), S - 1);
        int idx = (zc * S + yc) * S + xc;
        unsigned addr = (unsigned)(h * LENIN + base + idx) * 64u;  // bytes
        cw_s[wv][h * 132 + pt * 8 + c] = make_uint2(addr, __float_as_uint(w));
    }
    __syncthreads();

    // ---- phase 2: gather. lane = h(3b) | do8(3b): 8 lanes x 4 ch per head.
    const int h = lane >> 3, do8 = lane & 7;
    const char* vb = (const char*)value + do8 * 8;
    const uint2* cw = &cw_s[wv][h * 132];

    float acc0 = 0.f, acc1 = 0.f, acc2 = 0.f, acc3 = 0.f;
    #pragma unroll 4
    for (int pt = 0; pt < 16; ++pt) {
        #pragma unroll
        for (int c = 0; c < 8; ++c) {
            uint2 cwv = cw[pt * 8 + c];
            float w = __uint_as_float(cwv.y);
            f16x4 v = *(const f16x4*)(vb + cwv.x);
            acc0 += w * (float)v[0];
            acc1 += w * (float)v[1];
            acc2 += w * (float)v[2];
            acc3 += w * (float)v[3];
        }
    }
    f16x4 r;
    r[0] = (_Float16)acc0; r[1] = (_Float16)acc1;
    r[2] = (_Float16)acc2; r[3] = (_Float16)acc3;
    *(f16x4*)&oat[(size_t)q * DMODEL + h * DHEAD + do8 * 4] = r;
}

extern "C" void kernel_launch(void* const* d_in, const int* in_sizes, int n_in,
                              void* d_out, int out_size, void* d_ws, size_t ws_size,
                              hipStream_t stream) {
    const float* query         = (const float*)d_in[0];
    const float* refpts        = (const float*)d_in[1];
    const float* input_flatten = (const float*)d_in[2];
    const float* w_value       = (const float*)d_in[3];
    const float* b_value       = (const float*)d_in[4];
    const float* w_off         = (const float*)d_in[5];
    const float* b_off         = (const float*)d_in[6];
    const float* w_attn        = (const float*)d_in[7];
    const float* b_attn        = (const float*)d_in[8];
    const float* w_out         = (const float*)d_in[9];
    const float* b_out         = (const float*)d_in[10];

    _Float16* valueH = (_Float16*)d_ws;                    // 9,584,640 halfs (head-major)
    _Float16* wvT    = valueH + (size_t)LENIN * DMODEL;    //    65,536
    _Float16* catT   = wvT + 256 * 256;                    //   131,072
    _Float16* wuT    = catT + 512 * 256;                   //    65,536
    float*    proj   = (float*)(wuT + 256 * 256);          // 2,048,000 floats
    _Float16* oatH   = (_Float16*)(proj + (size_t)NQ * NPROJ); // 1,024,000 halfs
    // total ~29.9 MB of workspace

    cast_transpose_all<<<dim3(16, 4), 256, 0, stream>>>(
        w_value, w_off, w_attn, w_out, wvT, catT, wuT);

    gemm_mfma<float, _Float16, true><<<dim3(LENIN / 64, 1), 256, 0, stream>>>(
        input_flatten, wvT, b_value, b_value, 256, valueH, LENIN, DMODEL);

    gemm_mfma<float, float, false><<<dim3((NQ + 63) / 64, 2), 256, 0, stream>>>(
        query, catT, b_off, b_attn, NOFF, proj, NQ, NPROJ);

    sample_fused2<<<NQ / 4, 256, 0, stream>>>(valueH, proj, refpts, oatH);

    gemm_mfma<_Float16, float, false><<<dim3((NQ + 63) / 64, 1), 256, 0, stream>>>(
        oatH, wuT, b_out, b_out, 256, (float*)d_out, NQ, DMODEL);
}